// Round 1
// baseline (658.096 us; speedup 1.0000x reference)
//
#include <hip/hip_runtime.h>
#include <cstdint>
#include <cstddef>

// Static problem geometry
#define LEN_IN  21760
#define BATCH   2
#define MROWS   (BATCH * LEN_IN)   // 43520 = 64 * 680
// Levels: (128,128),(64,64),(32,32),(16,16); starts 0,16384,20480,21504

typedef _Float16 hv8 __attribute__((ext_vector_type(8)));   // 8 f16
typedef float    fv4 __attribute__((ext_vector_type(4)));

#define WAIT_LGKM0() __builtin_amdgcn_s_waitcnt(0xC07F)   // lgkmcnt(0) only
#define RAW_BARRIER() __builtin_amdgcn_s_barrier()

// ---------------------------------------------------------------------------
// Weight prep: coalesced 64x64 LDS transpose. K-major [K][N] -> [N][K] f16.
// Woff -> f16-split: rows [0,256) = hi, [256,512) = lo residual.
// WaT lands contiguously after WoffT2 so the fused GEMM sees B rows 512..639.
// ---------------------------------------------------------------------------
__global__ __launch_bounds__(256) void cvt_weights(
    const float* __restrict__ Wv, const float* __restrict__ Woff,
    const float* __restrict__ Wa, const float* __restrict__ Wo,
    _Float16* __restrict__ WvT, _Float16* __restrict__ WoffT2,
    _Float16* __restrict__ WaT, _Float16* __restrict__ WoT)
{
  __shared__ float t[64][65];
  const int id = blockIdx.x, tid = threadIdx.x;
  const int c = tid & 63, r4 = tid >> 6;

  const float* src; _Float16* dst; int N; bool split = false; int nt, kt;
  if (id < 16)      { src = Wv;   dst = WvT;    N = 256; nt = id & 3;        kt = id >> 2; }
  else if (id < 32) { src = Woff; dst = WoffT2; N = 256; nt = (id - 16) & 3; kt = (id - 16) >> 2; split = true; }
  else if (id < 40) { src = Wa;   dst = WaT;    N = 128; nt = (id - 32) & 1; kt = (id - 32) >> 1; }
  else              { src = Wo;   dst = WoT;    N = 256; nt = (id - 40) & 3; kt = (id - 40) >> 2; }
  const int nb = nt * 64, kb = kt * 64;

#pragma unroll
  for (int rr = 0; rr < 16; ++rr) {
    const int r = rr * 4 + r4;
    t[r][c] = src[(size_t)(kb + r) * N + nb + c];
  }
  __syncthreads();
#pragma unroll
  for (int rr = 0; rr < 16; ++rr) {
    const int r = rr * 4 + r4;
    const float v = t[c][r];
    const _Float16 h = (_Float16)v;
    dst[(size_t)(nb + r) * 256 + kb + c] = h;
    if (split)
      dst[(size_t)(256 + nb + r) * 256 + kb + c] = (_Float16)(v - (float)h);
  }
}

// ---------------------------------------------------------------------------
// Pipelined f16 MFMA GEMM, 64 x 128 tile, 256 thr = 4 waves (cols 32 each).
// Register pipelines: A 3-deep (HBM, ~3-iter slack), B 2-deep (L2, ~2-iter).
// CRITICAL: loads issued in NEED ORDER (B(it+2) before A(it+3)) so in-order
// vmcnt retirement never drains young A loads.
// LDS double-buffered; ONE raw barrier per iter, lgkmcnt(0)-only wait.
// NTOT: full output width. AF32: A fp32 (cvt in regs) else f16.
// OUTMODE 0: fp32 row-major; 1: f16 row-major; 2: f16 head planes.
// ---------------------------------------------------------------------------
template<int NTOT, int AF32, int OUTMODE>
__global__ __launch_bounds__(256) void gemm_pipe(
    const void* __restrict__ Ap, const _Float16* __restrict__ Bt,
    const float* __restrict__ bias, void* __restrict__ Cout)
{
  __shared__ _Float16 As[2][64 * 40];
  __shared__ _Float16 Bs[2][128 * 40];

  const int tid = threadIdx.x, lane = tid & 63, wave = tid >> 6;
  const int l15 = lane & 15, quad = lane >> 4;
  const int wc = wave * 32;
  const int rowBase = blockIdx.x * 64;
  const int colBase = blockIdx.y * 128;
  const int rs = tid >> 2, ks = (tid & 3) * 8;

  const float*    A32 = (const float*)Ap;
  const _Float16* A16 = (const _Float16*)Ap;

  float4 pa[3][2]; hv8 pa16[3]; hv8 pb[2][2];

  auto issueA = [&](int it) {
    const int k0 = it * 32, s = it % 3;
    if constexpr (AF32) {
      pa[s][0] = *(const float4*)&A32[(size_t)(rowBase + rs) * 256 + k0 + ks];
      pa[s][1] = *(const float4*)&A32[(size_t)(rowBase + rs) * 256 + k0 + ks + 4];
    } else {
      pa16[s] = *(const hv8*)&A16[(size_t)(rowBase + rs) * 256 + k0 + ks];
    }
  };
  auto issueB = [&](int it) {
    const int k0 = it * 32, s = it & 1;
#pragma unroll
    for (int p = 0; p < 2; ++p)
      pb[s][p] = *(const hv8*)&Bt[(size_t)(colBase + p * 64 + rs) * 256 + k0 + ks];
  };

  // Preamble in need order
  issueA(0); issueB(0); issueA(1); issueB(1); issueA(2);

  fv4 acc[4][2] = {};

#pragma unroll
  for (int it = 0; it < 8; ++it) {
    const int sb = it & 1, sa = it % 3;
    if constexpr (AF32) {
      const float4 f0 = pa[sa][0], f1 = pa[sa][1];
      const float fa[8] = {f0.x, f0.y, f0.z, f0.w, f1.x, f1.y, f1.z, f1.w};
      hv8 h;
#pragma unroll
      for (int e = 0; e < 8; ++e) h[e] = (_Float16)fa[e];
      *(hv8*)&As[sb][rs * 40 + ks] = h;
    } else {
      *(hv8*)&As[sb][rs * 40 + ks] = pa16[sa];
    }
#pragma unroll
    for (int p = 0; p < 2; ++p)
      *(hv8*)&Bs[sb][(p * 64 + rs) * 40 + ks] = pb[sb][p];
    if (it + 2 < 8) issueB(it + 2);   // need order: B first,
    if (it + 3 < 8) issueA(it + 3);   // then A
    WAIT_LGKM0();
    RAW_BARRIER();

    hv8 af[4];
#pragma unroll
    for (int i = 0; i < 4; ++i)
      af[i] = *(const hv8*)&As[sb][(i * 16 + l15) * 40 + quad * 8];
#pragma unroll
    for (int j = 0; j < 2; ++j) {
      const hv8 bf = *(const hv8*)&Bs[sb][(wc + j * 16 + l15) * 40 + quad * 8];
#pragma unroll
      for (int i = 0; i < 4; ++i)
        acc[i][j] = __builtin_amdgcn_mfma_f32_16x16x32_f16(af[i], bf, acc[i][j], 0, 0, 0);
    }
    // Double buffer: reads of buf sb complete before next iter's lgkm wait,
    // so writes to buf sb at it+2 are safe with one barrier per iter.
  }

#pragma unroll
  for (int j = 0; j < 2; ++j) {
    const int col = colBase + wc + j * 16 + l15;
    const float bj = bias[col];
#pragma unroll
    for (int i = 0; i < 4; ++i)
#pragma unroll
      for (int rg = 0; rg < 4; ++rg) {
        const int row = rowBase + i * 16 + quad * 4 + rg;
        const float v = acc[i][j][rg] + bj;
        if constexpr (OUTMODE == 0) {
          ((float*)Cout)[(size_t)row * NTOT + col] = v;
        } else if constexpr (OUTMODE == 1) {
          ((_Float16*)Cout)[(size_t)row * NTOT + col] = (_Float16)v;
        } else {
          const int n = (row >= LEN_IN) ? 1 : 0;
          const int pix = row - n * LEN_IN;
          const int m = col >> 5, d = col & 31;
          ((_Float16*)Cout)[((size_t)(n * 8 + m) * LEN_IN + pix) * 32 + d] = (_Float16)v;
        }
      }
  }
}

// ---------------------------------------------------------------------------
// FUSED offsets + logits GEMM: one pass over query (A, fp32).
// Grid (680, 3): y=0,1 -> offset coord columns, f16-split A and B (3 MFMAs).
// y=2 -> logits columns, plain hi-only path (1 MFMA), f16 out.
// B2 = [640][256] f16: rows 0..255 Woff-hi, 256..511 Woff-lo, 512..639 Wa.
// Single-buffer LDS (30.7 KB), two raw barriers/iter, need-order pipeline.
// ---------------------------------------------------------------------------
__global__ __launch_bounds__(256) void gemm_offs_logits(
    const float* __restrict__ A, const _Float16* __restrict__ B2,
    const float* __restrict__ boff, const float* __restrict__ ba,
    const float* __restrict__ refpts,
    float* __restrict__ C, _Float16* __restrict__ logits16)
{
  __shared__ _Float16 Ash[64 * 40], Asl[64 * 40];
  __shared__ _Float16 Bs[256 * 40];   // offs: rows 0-127 hi, 128-255 lo. logits: rows 0-127.

  const bool offs = (blockIdx.y < 2);
  const int np = offs ? 4 : 2;        // B row-groups staged per iter
  const int tid = threadIdx.x, lane = tid & 63, wave = tid >> 6;
  const int l15 = lane & 15, quad = lane >> 4;
  const int wc = wave * 32;
  const int rowBase = blockIdx.x * 64;
  const int colBase = offs ? blockIdx.y * 128 : 0;
  const int rs = tid >> 2, ks = (tid & 3) * 8;

  float4 pa[3][2]; hv8 pb[2][4];

  auto issueA = [&](int it) {
    const int k0 = it * 32, s = it % 3;
    pa[s][0] = *(const float4*)&A[(size_t)(rowBase + rs) * 256 + k0 + ks];
    pa[s][1] = *(const float4*)&A[(size_t)(rowBase + rs) * 256 + k0 + ks + 4];
  };
  auto issueB = [&](int it) {
    const int k0 = it * 32, s = it & 1;
#pragma unroll
    for (int p = 0; p < 4; ++p) {
      if (p >= np) break;
      const int grow = offs
          ? ((p < 2) ? (colBase + p * 64 + rs) : (256 + colBase + (p - 2) * 64 + rs))
          : (512 + p * 64 + rs);
      pb[s][p] = *(const hv8*)&B2[(size_t)grow * 256 + k0 + ks];
    }
  };

  issueA(0); issueB(0); issueA(1); issueB(1); issueA(2);

  fv4 acc[4][2] = {};

#pragma unroll
  for (int it = 0; it < 8; ++it) {
    const int sa = it % 3, s2 = it & 1;
    {
      const float4 f0 = pa[sa][0], f1 = pa[sa][1];
      const float fa[8] = {f0.x, f0.y, f0.z, f0.w, f1.x, f1.y, f1.z, f1.w};
      hv8 hh, ll;
#pragma unroll
      for (int e = 0; e < 8; ++e) {
        hh[e] = (_Float16)fa[e];
        ll[e] = (_Float16)(fa[e] - (float)hh[e]);
      }
      *(hv8*)&Ash[rs * 40 + ks] = hh;
      if (offs) *(hv8*)&Asl[rs * 40 + ks] = ll;
    }
#pragma unroll
    for (int p = 0; p < 4; ++p) {
      if (p >= np) break;
      *(hv8*)&Bs[(p * 64 + rs) * 40 + ks] = pb[s2][p];
    }
    if (it + 2 < 8) issueB(it + 2);
    if (it + 3 < 8) issueA(it + 3);
    WAIT_LGKM0();
    RAW_BARRIER();

    hv8 ah[4];
#pragma unroll
    for (int i = 0; i < 4; ++i)
      ah[i] = *(const hv8*)&Ash[(i * 16 + l15) * 40 + quad * 8];

    if (offs) {
      hv8 al[4];
#pragma unroll
      for (int i = 0; i < 4; ++i)
        al[i] = *(const hv8*)&Asl[(i * 16 + l15) * 40 + quad * 8];
#pragma unroll
      for (int j = 0; j < 2; ++j) {
        const hv8 bh = *(const hv8*)&Bs[(wc + j * 16 + l15) * 40 + quad * 8];
        const hv8 bl = *(const hv8*)&Bs[(128 + wc + j * 16 + l15) * 40 + quad * 8];
#pragma unroll
        for (int i = 0; i < 4; ++i) {
          acc[i][j] = __builtin_amdgcn_mfma_f32_16x16x32_f16(ah[i], bh, acc[i][j], 0, 0, 0);
          acc[i][j] = __builtin_amdgcn_mfma_f32_16x16x32_f16(ah[i], bl, acc[i][j], 0, 0, 0);
          acc[i][j] = __builtin_amdgcn_mfma_f32_16x16x32_f16(al[i], bh, acc[i][j], 0, 0, 0);
        }
      }
    } else {
#pragma unroll
      for (int j = 0; j < 2; ++j) {
        const hv8 bh = *(const hv8*)&Bs[(wc + j * 16 + l15) * 40 + quad * 8];
#pragma unroll
        for (int i = 0; i < 4; ++i)
          acc[i][j] = __builtin_amdgcn_mfma_f32_16x16x32_f16(ah[i], bh, acc[i][j], 0, 0, 0);
      }
    }
    WAIT_LGKM0();   // frag reads done before next iter overwrites (single buf)
    RAW_BARRIER();
  }

  if (offs) {
    // col c = (((m*4+l)*4+p)*2+xy); write (acc + boff + ref) * W - 0.5
#pragma unroll
    for (int j = 0; j < 2; ++j) {
      const int c = colBase + wc + j * 16 + l15;
      const int xy = c & 1, l = (c >> 3) & 3;
      const float Wl = (float)(128 >> l);
      const float bj = boff[c];
#pragma unroll
      for (int i = 0; i < 4; ++i)
#pragma unroll
        for (int rg = 0; rg < 4; ++rg) {
          const int row = rowBase + i * 16 + quad * 4 + rg;
          const float ref = refpts[(size_t)row * 8 + l * 2 + xy];
          C[(size_t)row * 256 + c] = (acc[i][j][rg] + bj + ref) * Wl - 0.5f;
        }
    }
  } else {
#pragma unroll
    for (int j = 0; j < 2; ++j) {
      const int col = wc + j * 16 + l15;
      const float bj = ba[col];
#pragma unroll
      for (int i = 0; i < 4; ++i)
#pragma unroll
        for (int rg = 0; rg < 4; ++rg) {
          const int row = rowBase + i * 16 + quad * 4 + rg;
          logits16[(size_t)row * 128 + col] = (_Float16)(acc[i][j][rg] + bj);
        }
    }
  }
}

// ---------------------------------------------------------------------------
// Sampler: conflict-free, gather/VALU-bound. 2-deep software-pipelined
// gather loop: stage p+1's 4 loads while consuming p's FMAs, keeping ~8
// loads in flight (VGPR 24 -> ~64, still under the (256,6) cap of 85).
// ---------------------------------------------------------------------------
__global__ __launch_bounds__(256, 6) void sample_kernel(
    const _Float16* __restrict__ value16,  // head planes
    const float* __restrict__ coords,      // (B, LQ, 256) pixel coords
    const _Float16* __restrict__ logits16, // (B, LQ, 128)
    _Float16* __restrict__ outp16)         // (B, LQ, 256)
{
  __shared__ unsigned s_pair[4096];
  __shared__ float    s_attn[1024];

  const int tid = threadIdx.x;
  const int qBase = blockIdx.x * 8;

  if (tid < 64) {   // softmax per (q,m) over 16
    const hv8* lp = (const hv8*)&logits16[(size_t)(qBase + (tid >> 3)) * 128 + (tid & 7) * 16];
    const hv8 w0 = lp[0], w1 = lp[1];
    float w[16];
#pragma unroll
    for (int e = 0; e < 8; ++e) { w[e] = (float)w0[e]; w[8 + e] = (float)w1[e]; }
    float mx = w[0];
#pragma unroll
    for (int i = 1; i < 16; ++i) mx = fmaxf(mx, w[i]);
    float sum = 0.f;
#pragma unroll
    for (int i = 0; i < 16; ++i) { w[i] = expf(w[i] - mx); sum += w[i]; }
    const float inv = 1.f / sum;
#pragma unroll
    for (int p = 0; p < 16; ++p) s_attn[p * 64 + tid] = w[p] * inv;
  }
  __syncthreads();

#pragma unroll
  for (int k = 0; k < 4; ++k) {
    const int i = tid + 256 * k;
    const int p = i >> 6, q = (i >> 3) & 7, m = i & 7;
    const int l = p >> 2, pp = p & 3;
    const int qg = qBase + q;
    const float2 of = *(const float2*)&coords[(size_t)qg * 256 + ((m * 4 + l) * 4 + pp) * 2];
    const float aw = s_attn[i];
    const int W = 128 >> l;
    const int st = (l == 0) ? 0 : (l == 1) ? 16384 : (l == 2) ? 20480 : 21504;
    const float xf = floorf(of.x), yf = floorf(of.y);
    const int x0 = (int)xf, y0 = (int)yf;
    const float wx = of.x - xf, wy = of.y - yf;
    uint4 rec;
    unsigned* rp = &rec.x;
#pragma unroll
    for (int c = 0; c < 4; ++c) {
      const int dx = c & 1, dy = c >> 1;
      const int xi = x0 + dx, yi = y0 + dy;
      const bool valid = (xi >= 0) & (xi < W) & (yi >= 0) & (yi < W);
      const float w = (dx ? wx : 1.f - wx) * (dy ? wy : 1.f - wy) * aw;
      union { _Float16 h; unsigned short s; } pk;
      pk.h = (_Float16)w;
      const unsigned idx = (unsigned)(st + yi * W + xi);
      rp[c] = valid ? (idx | ((unsigned)pk.s << 16)) : 0u;
    }
    *(uint4*)&s_pair[i * 4] = rec;
  }
  __syncthreads();

  const int wave = tid >> 6, lane = tid & 63;
  const int qloc = wave * 2 + (lane >> 5);
  const int sub = lane & 31, m = sub >> 2, j = sub & 3;
  const int qg = qBase + qloc;
  const int n = (qg >= LEN_IN) ? 1 : 0;
  const char* base = (const char*)value16 + (size_t)(n * 8 + m) * LEN_IN * 64 + j * 16;
  const int lb = qloc * 8 + m;

  float acc8[8] = {0.f, 0.f, 0.f, 0.f, 0.f, 0.f, 0.f, 0.f};

  // 2-deep pipeline: stage(p+1) issued before consume(p).
  hv8  v0[4], v1[4];
  float w0[4], w1[4];

  {
    const uint4 uf = *(const uint4*)&s_pair[(0 * 64 + lb) * 4];
    const unsigned uu[4] = {uf.x, uf.y, uf.z, uf.w};
#pragma unroll
    for (int c = 0; c < 4; ++c) {
      union { unsigned short s; _Float16 h; } pk;
      pk.s = (unsigned short)(uu[c] >> 16);
      w0[c] = (float)pk.h;
      v0[c] = *(const hv8*)(base + (size_t)(uu[c] & 32767u) * 64);
    }
  }

#pragma unroll
  for (int p = 0; p < 15; ++p) {
    const uint4 un = *(const uint4*)&s_pair[((p + 1) * 64 + lb) * 4];
    const unsigned uu[4] = {un.x, un.y, un.z, un.w};
    if ((p & 1) == 0) {
      // stage -> v1/w1, consume v0/w0
#pragma unroll
      for (int c = 0; c < 4; ++c) {
        union { unsigned short s; _Float16 h; } pk;
        pk.s = (unsigned short)(uu[c] >> 16);
        w1[c] = (float)pk.h;
        v1[c] = *(const hv8*)(base + (size_t)(uu[c] & 32767u) * 64);
      }
#pragma unroll
      for (int c = 0; c < 4; ++c)
#pragma unroll
        for (int e = 0; e < 8; ++e)
          acc8[e] = fmaf(w0[c], (float)v0[c][e], acc8[e]);
    } else {
      // stage -> v0/w0, consume v1/w1
#pragma unroll
      for (int c = 0; c < 4; ++c) {
        union { unsigned short s; _Float16 h; } pk;
        pk.s = (unsigned short)(uu[c] >> 16);
        w0[c] = (float)pk.h;
        v0[c] = *(const hv8*)(base + (size_t)(uu[c] & 32767u) * 64);
      }
#pragma unroll
      for (int c = 0; c < 4; ++c)
#pragma unroll
        for (int e = 0; e < 8; ++e)
          acc8[e] = fmaf(w1[c], (float)v1[c][e], acc8[e]);
    }
  }
  // tail: p=15 sits in v1/w1 (staged at p=14)
#pragma unroll
  for (int c = 0; c < 4; ++c)
#pragma unroll
    for (int e = 0; e < 8; ++e)
      acc8[e] = fmaf(w1[c], (float)v1[c][e], acc8[e]);

  hv8 o;
#pragma unroll
  for (int e = 0; e < 8; ++e) o[e] = (_Float16)acc8[e];
  *(hv8*)&outp16[(size_t)qg * 256 + m * 32 + j * 8] = o;
}

// ---------------------------------------------------------------------------
extern "C" void kernel_launch(void* const* d_in, const int* in_sizes, int n_in,
                              void* d_out, int out_size, void* d_ws, size_t ws_size,
                              hipStream_t stream) {
  const float* query   = (const float*)d_in[0];
  const float* refpts  = (const float*)d_in[1];
  const float* flatten = (const float*)d_in[2];
  const float* Wv   = (const float*)d_in[5];
  const float* bv   = (const float*)d_in[6];
  const float* Woff = (const float*)d_in[7];
  const float* boff = (const float*)d_in[8];
  const float* Wa   = (const float*)d_in[9];
  const float* ba   = (const float*)d_in[10];
  const float* Wo   = (const float*)d_in[11];
  const float* bo   = (const float*)d_in[12];
  float* out = (float*)d_out;

  // Workspace (~101 MB): value16 | coords | logits16 | outp16 | weights
  const size_t NE = (size_t)MROWS * 256;            // 11,141,120
  _Float16* value16  = (_Float16*)d_ws;             // NE halves (head planes)
  float*    coords   = (float*)(value16 + NE);      // NE floats
  _Float16* logits16 = (_Float16*)(coords + NE);    // NE/2 halves
  _Float16* outp16   = logits16 + NE / 2;           // NE halves
  _Float16* WvT      = outp16 + NE;                 // 256*256
  _Float16* WoffT2   = WvT + 256 * 256;             // 512*256 (hi|lo)
  _Float16* WaT      = WoffT2 + 512 * 256;          // 128*256 (contig after WoffT2!)
  _Float16* WoT      = WaT + 128 * 256;             // 256*256

  const dim3 blk(256);
  const int mtiles = MROWS / 64;   // 680

  cvt_weights<<<dim3(56), blk, 0, stream>>>(Wv, Woff, Wa, Wo, WvT, WoffT2, WaT, WoT);

  // value = f16(flatten @ Wv + bv) -> head planes
  gemm_pipe<256, 1, 2><<<dim3(mtiles, 2), blk, 0, stream>>>(flatten, WvT, bv, value16);
  // FUSED: coords = (query @ Woff + boff + ref) * W - 0.5  AND
  //        logits = f16(query @ Wa + ba)   -- one pass over query
  gemm_offs_logits<<<dim3(mtiles, 3), blk, 0, stream>>>(query, WoffT2, boff, ba, refpts,
                                                        coords, logits16);
  // sampling -> out_pre (f16)
  sample_kernel<<<dim3(MROWS / 8), blk, 0, stream>>>(value16, coords, logits16, outp16);
  // out = out_pre @ Wo + bo (fp32 to d_out)
  gemm_pipe<256, 0, 0><<<dim3(mtiles, 2), blk, 0, stream>>>(outp16, WoT, bo, out);
}

// Round 2
// 639.920 us; speedup vs baseline: 1.0284x; 1.0284x over previous
//
#include <hip/hip_runtime.h>
#include <cstdint>
#include <cstddef>

// Static problem geometry
#define LEN_IN  21760
#define BATCH   2
#define MROWS   (BATCH * LEN_IN)   // 43520 = 64 * 680
// Levels: (128,128),(64,64),(32,32),(16,16); starts 0,16384,20480,21504

typedef _Float16 hv8 __attribute__((ext_vector_type(8)));   // 8 f16
typedef float    fv4 __attribute__((ext_vector_type(4)));

#define WAIT_LGKM0() __builtin_amdgcn_s_waitcnt(0xC07F)   // lgkmcnt(0) only
#define RAW_BARRIER() __builtin_amdgcn_s_barrier()

// ---------------------------------------------------------------------------
// Weight prep: coalesced 64x64 LDS transpose. K-major [K][N] -> [N][K] f16.
// Woff -> f16-split: rows [0,256) = hi, [256,512) = lo residual.
// WaT lands contiguously after WoffT2 so the fused GEMM sees B rows 512..639.
// ---------------------------------------------------------------------------
__global__ __launch_bounds__(256) void cvt_weights(
    const float* __restrict__ Wv, const float* __restrict__ Woff,
    const float* __restrict__ Wa, const float* __restrict__ Wo,
    _Float16* __restrict__ WvT, _Float16* __restrict__ WoffT2,
    _Float16* __restrict__ WaT, _Float16* __restrict__ WoT)
{
  __shared__ float t[64][65];
  const int id = blockIdx.x, tid = threadIdx.x;
  const int c = tid & 63, r4 = tid >> 6;

  const float* src; _Float16* dst; int N; bool split = false; int nt, kt;
  if (id < 16)      { src = Wv;   dst = WvT;    N = 256; nt = id & 3;        kt = id >> 2; }
  else if (id < 32) { src = Woff; dst = WoffT2; N = 256; nt = (id - 16) & 3; kt = (id - 16) >> 2; split = true; }
  else if (id < 40) { src = Wa;   dst = WaT;    N = 128; nt = (id - 32) & 1; kt = (id - 32) >> 1; }
  else              { src = Wo;   dst = WoT;    N = 256; nt = (id - 40) & 3; kt = (id - 40) >> 2; }
  const int nb = nt * 64, kb = kt * 64;

#pragma unroll
  for (int rr = 0; rr < 16; ++rr) {
    const int r = rr * 4 + r4;
    t[r][c] = src[(size_t)(kb + r) * N + nb + c];
  }
  __syncthreads();
#pragma unroll
  for (int rr = 0; rr < 16; ++rr) {
    const int r = rr * 4 + r4;
    const float v = t[c][r];
    const _Float16 h = (_Float16)v;
    dst[(size_t)(nb + r) * 256 + kb + c] = h;
    if (split)
      dst[(size_t)(256 + nb + r) * 256 + kb + c] = (_Float16)(v - (float)h);
  }
}

// ---------------------------------------------------------------------------
// Pipelined f16 MFMA GEMM, 64 x 128 tile, 256 thr = 4 waves (cols 32 each).
// Register pipelines: A 3-deep (HBM, ~3-iter slack), B 2-deep (L2, ~2-iter).
// CRITICAL: loads issued in NEED ORDER (B(it+2) before A(it+3)) so in-order
// vmcnt retirement never drains young A loads.
// LDS double-buffered; ONE raw barrier per iter, lgkmcnt(0)-only wait.
// NTOT: full output width. AF32: A fp32 (cvt in regs) else f16.
// OUTMODE 0: fp32 row-major; 1: f16 row-major; 2: f16 head planes.
// ---------------------------------------------------------------------------
template<int NTOT, int AF32, int OUTMODE>
__global__ __launch_bounds__(256) void gemm_pipe(
    const void* __restrict__ Ap, const _Float16* __restrict__ Bt,
    const float* __restrict__ bias, void* __restrict__ Cout)
{
  __shared__ _Float16 As[2][64 * 40];
  __shared__ _Float16 Bs[2][128 * 40];

  const int tid = threadIdx.x, lane = tid & 63, wave = tid >> 6;
  const int l15 = lane & 15, quad = lane >> 4;
  const int wc = wave * 32;
  const int rowBase = blockIdx.x * 64;
  const int colBase = blockIdx.y * 128;
  const int rs = tid >> 2, ks = (tid & 3) * 8;

  const float*    A32 = (const float*)Ap;
  const _Float16* A16 = (const _Float16*)Ap;

  float4 pa[3][2]; hv8 pa16[3]; hv8 pb[2][2];

  auto issueA = [&](int it) {
    const int k0 = it * 32, s = it % 3;
    if constexpr (AF32) {
      pa[s][0] = *(const float4*)&A32[(size_t)(rowBase + rs) * 256 + k0 + ks];
      pa[s][1] = *(const float4*)&A32[(size_t)(rowBase + rs) * 256 + k0 + ks + 4];
    } else {
      pa16[s] = *(const hv8*)&A16[(size_t)(rowBase + rs) * 256 + k0 + ks];
    }
  };
  auto issueB = [&](int it) {
    const int k0 = it * 32, s = it & 1;
#pragma unroll
    for (int p = 0; p < 2; ++p)
      pb[s][p] = *(const hv8*)&Bt[(size_t)(colBase + p * 64 + rs) * 256 + k0 + ks];
  };

  // Preamble in need order
  issueA(0); issueB(0); issueA(1); issueB(1); issueA(2);

  fv4 acc[4][2] = {};

#pragma unroll
  for (int it = 0; it < 8; ++it) {
    const int sb = it & 1, sa = it % 3;
    if constexpr (AF32) {
      const float4 f0 = pa[sa][0], f1 = pa[sa][1];
      const float fa[8] = {f0.x, f0.y, f0.z, f0.w, f1.x, f1.y, f1.z, f1.w};
      hv8 h;
#pragma unroll
      for (int e = 0; e < 8; ++e) h[e] = (_Float16)fa[e];
      *(hv8*)&As[sb][rs * 40 + ks] = h;
    } else {
      *(hv8*)&As[sb][rs * 40 + ks] = pa16[sa];
    }
#pragma unroll
    for (int p = 0; p < 2; ++p)
      *(hv8*)&Bs[sb][(p * 64 + rs) * 40 + ks] = pb[sb][p];
    if (it + 2 < 8) issueB(it + 2);   // need order: B first,
    if (it + 3 < 8) issueA(it + 3);   // then A
    WAIT_LGKM0();
    RAW_BARRIER();

    hv8 af[4];
#pragma unroll
    for (int i = 0; i < 4; ++i)
      af[i] = *(const hv8*)&As[sb][(i * 16 + l15) * 40 + quad * 8];
#pragma unroll
    for (int j = 0; j < 2; ++j) {
      const hv8 bf = *(const hv8*)&Bs[sb][(wc + j * 16 + l15) * 40 + quad * 8];
#pragma unroll
      for (int i = 0; i < 4; ++i)
        acc[i][j] = __builtin_amdgcn_mfma_f32_16x16x32_f16(af[i], bf, acc[i][j], 0, 0, 0);
    }
    // Double buffer: reads of buf sb complete before next iter's lgkm wait,
    // so writes to buf sb at it+2 are safe with one barrier per iter.
  }

#pragma unroll
  for (int j = 0; j < 2; ++j) {
    const int col = colBase + wc + j * 16 + l15;
    const float bj = bias[col];
#pragma unroll
    for (int i = 0; i < 4; ++i)
#pragma unroll
      for (int rg = 0; rg < 4; ++rg) {
        const int row = rowBase + i * 16 + quad * 4 + rg;
        const float v = acc[i][j][rg] + bj;
        if constexpr (OUTMODE == 0) {
          ((float*)Cout)[(size_t)row * NTOT + col] = v;
        } else if constexpr (OUTMODE == 1) {
          ((_Float16*)Cout)[(size_t)row * NTOT + col] = (_Float16)v;
        } else {
          const int n = (row >= LEN_IN) ? 1 : 0;
          const int pix = row - n * LEN_IN;
          const int m = col >> 5, d = col & 31;
          ((_Float16*)Cout)[((size_t)(n * 8 + m) * LEN_IN + pix) * 32 + d] = (_Float16)v;
        }
      }
  }
}

// ---------------------------------------------------------------------------
// FUSED offsets + logits GEMM: one pass over query (A, fp32).
// Grid (680, 3): y=0,1 -> offset coord columns, f16-split A and B (3 MFMAs).
// y=2 -> logits columns, plain hi-only path (1 MFMA), f16 out.
// B2 = [640][256] f16: rows 0..255 Woff-hi, 256..511 Woff-lo, 512..639 Wa.
// Single-buffer LDS (30.7 KB), two raw barriers/iter, need-order pipeline.
// ---------------------------------------------------------------------------
__global__ __launch_bounds__(256) void gemm_offs_logits(
    const float* __restrict__ A, const _Float16* __restrict__ B2,
    const float* __restrict__ boff, const float* __restrict__ ba,
    const float* __restrict__ refpts,
    float* __restrict__ C, _Float16* __restrict__ logits16)
{
  __shared__ _Float16 Ash[64 * 40], Asl[64 * 40];
  __shared__ _Float16 Bs[256 * 40];   // offs: rows 0-127 hi, 128-255 lo. logits: rows 0-127.

  const bool offs = (blockIdx.y < 2);
  const int np = offs ? 4 : 2;        // B row-groups staged per iter
  const int tid = threadIdx.x, lane = tid & 63, wave = tid >> 6;
  const int l15 = lane & 15, quad = lane >> 4;
  const int wc = wave * 32;
  const int rowBase = blockIdx.x * 64;
  const int colBase = offs ? blockIdx.y * 128 : 0;
  const int rs = tid >> 2, ks = (tid & 3) * 8;

  float4 pa[3][2]; hv8 pb[2][4];

  auto issueA = [&](int it) {
    const int k0 = it * 32, s = it % 3;
    pa[s][0] = *(const float4*)&A[(size_t)(rowBase + rs) * 256 + k0 + ks];
    pa[s][1] = *(const float4*)&A[(size_t)(rowBase + rs) * 256 + k0 + ks + 4];
  };
  auto issueB = [&](int it) {
    const int k0 = it * 32, s = it & 1;
#pragma unroll
    for (int p = 0; p < 4; ++p) {
      if (p >= np) break;
      const int grow = offs
          ? ((p < 2) ? (colBase + p * 64 + rs) : (256 + colBase + (p - 2) * 64 + rs))
          : (512 + p * 64 + rs);
      pb[s][p] = *(const hv8*)&B2[(size_t)grow * 256 + k0 + ks];
    }
  };

  issueA(0); issueB(0); issueA(1); issueB(1); issueA(2);

  fv4 acc[4][2] = {};

#pragma unroll
  for (int it = 0; it < 8; ++it) {
    const int sa = it % 3, s2 = it & 1;
    {
      const float4 f0 = pa[sa][0], f1 = pa[sa][1];
      const float fa[8] = {f0.x, f0.y, f0.z, f0.w, f1.x, f1.y, f1.z, f1.w};
      hv8 hh, ll;
#pragma unroll
      for (int e = 0; e < 8; ++e) {
        hh[e] = (_Float16)fa[e];
        ll[e] = (_Float16)(fa[e] - (float)hh[e]);
      }
      *(hv8*)&Ash[rs * 40 + ks] = hh;
      if (offs) *(hv8*)&Asl[rs * 40 + ks] = ll;
    }
#pragma unroll
    for (int p = 0; p < 4; ++p) {
      if (p >= np) break;
      *(hv8*)&Bs[(p * 64 + rs) * 40 + ks] = pb[s2][p];
    }
    if (it + 2 < 8) issueB(it + 2);
    if (it + 3 < 8) issueA(it + 3);
    WAIT_LGKM0();
    RAW_BARRIER();

    hv8 ah[4];
#pragma unroll
    for (int i = 0; i < 4; ++i)
      ah[i] = *(const hv8*)&Ash[(i * 16 + l15) * 40 + quad * 8];

    if (offs) {
      hv8 al[4];
#pragma unroll
      for (int i = 0; i < 4; ++i)
        al[i] = *(const hv8*)&Asl[(i * 16 + l15) * 40 + quad * 8];
#pragma unroll
      for (int j = 0; j < 2; ++j) {
        const hv8 bh = *(const hv8*)&Bs[(wc + j * 16 + l15) * 40 + quad * 8];
        const hv8 bl = *(const hv8*)&Bs[(128 + wc + j * 16 + l15) * 40 + quad * 8];
#pragma unroll
        for (int i = 0; i < 4; ++i) {
          acc[i][j] = __builtin_amdgcn_mfma_f32_16x16x32_f16(ah[i], bh, acc[i][j], 0, 0, 0);
          acc[i][j] = __builtin_amdgcn_mfma_f32_16x16x32_f16(ah[i], bl, acc[i][j], 0, 0, 0);
          acc[i][j] = __builtin_amdgcn_mfma_f32_16x16x32_f16(al[i], bh, acc[i][j], 0, 0, 0);
        }
      }
    } else {
#pragma unroll
      for (int j = 0; j < 2; ++j) {
        const hv8 bh = *(const hv8*)&Bs[(wc + j * 16 + l15) * 40 + quad * 8];
#pragma unroll
        for (int i = 0; i < 4; ++i)
          acc[i][j] = __builtin_amdgcn_mfma_f32_16x16x32_f16(ah[i], bh, acc[i][j], 0, 0, 0);
      }
    }
    WAIT_LGKM0();   // frag reads done before next iter overwrites (single buf)
    RAW_BARRIER();
  }

  if (offs) {
    // col c = (((m*4+l)*4+p)*2+xy); write (acc + boff + ref) * W - 0.5
#pragma unroll
    for (int j = 0; j < 2; ++j) {
      const int c = colBase + wc + j * 16 + l15;
      const int xy = c & 1, l = (c >> 3) & 3;
      const float Wl = (float)(128 >> l);
      const float bj = boff[c];
#pragma unroll
      for (int i = 0; i < 4; ++i)
#pragma unroll
        for (int rg = 0; rg < 4; ++rg) {
          const int row = rowBase + i * 16 + quad * 4 + rg;
          const float ref = refpts[(size_t)row * 8 + l * 2 + xy];
          C[(size_t)row * 256 + c] = (acc[i][j][rg] + bj + ref) * Wl - 0.5f;
        }
    }
  } else {
#pragma unroll
    for (int j = 0; j < 2; ++j) {
      const int col = wc + j * 16 + l15;
      const float bj = ba[col];
#pragma unroll
      for (int i = 0; i < 4; ++i)
#pragma unroll
        for (int rg = 0; rg < 4; ++rg) {
          const int row = rowBase + i * 16 + quad * 4 + rg;
          logits16[(size_t)row * 128 + col] = (_Float16)(acc[i][j][rg] + bj);
        }
    }
  }
}

// ---------------------------------------------------------------------------
// Sampler helpers: named-register staging (NO arrays, NO branches in the
// pipeline body -> rule #20 safe; R1's array-based stages went to scratch).
// ---------------------------------------------------------------------------
__device__ __forceinline__ void stage4(
    const unsigned* s_pair, int lb, int p, const char* base,
    hv8& v0, hv8& v1, hv8& v2, hv8& v3,
    float& w0, float& w1, float& w2, float& w3)
{
  const uint4 u4 = *(const uint4*)&s_pair[(p * 64 + lb) * 4];
  union { unsigned short s; _Float16 h; } pk;
  pk.s = (unsigned short)(u4.x >> 16); w0 = (float)pk.h;
  v0 = *(const hv8*)(base + (size_t)(u4.x & 32767u) * 64);
  pk.s = (unsigned short)(u4.y >> 16); w1 = (float)pk.h;
  v1 = *(const hv8*)(base + (size_t)(u4.y & 32767u) * 64);
  pk.s = (unsigned short)(u4.z >> 16); w2 = (float)pk.h;
  v2 = *(const hv8*)(base + (size_t)(u4.z & 32767u) * 64);
  pk.s = (unsigned short)(u4.w >> 16); w3 = (float)pk.h;
  v3 = *(const hv8*)(base + (size_t)(u4.w & 32767u) * 64);
}

__device__ __forceinline__ void consume4(
    float (&acc8)[8],
    hv8 v0, hv8 v1, hv8 v2, hv8 v3,
    float w0, float w1, float w2, float w3)
{
#pragma unroll
  for (int e = 0; e < 8; ++e) {
    acc8[e] = fmaf(w0, (float)v0[e], acc8[e]);
    acc8[e] = fmaf(w1, (float)v1[e], acc8[e]);
    acc8[e] = fmaf(w2, (float)v2[e], acc8[e]);
    acc8[e] = fmaf(w3, (float)v3[e], acc8[e]);
  }
}

// ---------------------------------------------------------------------------
// Sampler: conflict-free, gather/VALU-bound. 2-deep pipeline with fully
// named scalar stages (A/B), manual 2x unroll: stage(p+1) issues its 4
// gathers before consume(p)'s 32 FMAs -> ~8 loads in flight, no scratch.
// ---------------------------------------------------------------------------
__global__ __launch_bounds__(256, 6) void sample_kernel(
    const _Float16* __restrict__ value16,  // head planes
    const float* __restrict__ coords,      // (B, LQ, 256) pixel coords
    const _Float16* __restrict__ logits16, // (B, LQ, 128)
    _Float16* __restrict__ outp16)         // (B, LQ, 256)
{
  __shared__ unsigned s_pair[4096];
  __shared__ float    s_attn[1024];

  const int tid = threadIdx.x;
  const int qBase = blockIdx.x * 8;

  if (tid < 64) {   // softmax per (q,m) over 16
    const hv8* lp = (const hv8*)&logits16[(size_t)(qBase + (tid >> 3)) * 128 + (tid & 7) * 16];
    const hv8 w0 = lp[0], w1 = lp[1];
    float w[16];
#pragma unroll
    for (int e = 0; e < 8; ++e) { w[e] = (float)w0[e]; w[8 + e] = (float)w1[e]; }
    float mx = w[0];
#pragma unroll
    for (int i = 1; i < 16; ++i) mx = fmaxf(mx, w[i]);
    float sum = 0.f;
#pragma unroll
    for (int i = 0; i < 16; ++i) { w[i] = expf(w[i] - mx); sum += w[i]; }
    const float inv = 1.f / sum;
#pragma unroll
    for (int p = 0; p < 16; ++p) s_attn[p * 64 + tid] = w[p] * inv;
  }
  __syncthreads();

#pragma unroll
  for (int k = 0; k < 4; ++k) {
    const int i = tid + 256 * k;
    const int p = i >> 6, q = (i >> 3) & 7, m = i & 7;
    const int l = p >> 2, pp = p & 3;
    const int qg = qBase + q;
    const float2 of = *(const float2*)&coords[(size_t)qg * 256 + ((m * 4 + l) * 4 + pp) * 2];
    const float aw = s_attn[i];
    const int W = 128 >> l;
    const int st = (l == 0) ? 0 : (l == 1) ? 16384 : (l == 2) ? 20480 : 21504;
    const float xf = floorf(of.x), yf = floorf(of.y);
    const int x0 = (int)xf, y0 = (int)yf;
    const float wx = of.x - xf, wy = of.y - yf;
    uint4 rec;
    unsigned* rp = &rec.x;
#pragma unroll
    for (int c = 0; c < 4; ++c) {
      const int dx = c & 1, dy = c >> 1;
      const int xi = x0 + dx, yi = y0 + dy;
      const bool valid = (xi >= 0) & (xi < W) & (yi >= 0) & (yi < W);
      const float w = (dx ? wx : 1.f - wx) * (dy ? wy : 1.f - wy) * aw;
      union { _Float16 h; unsigned short s; } pk;
      pk.h = (_Float16)w;
      const unsigned idx = (unsigned)(st + yi * W + xi);
      rp[c] = valid ? (idx | ((unsigned)pk.s << 16)) : 0u;
    }
    *(uint4*)&s_pair[i * 4] = rec;
  }
  __syncthreads();

  const int wave = tid >> 6, lane = tid & 63;
  const int qloc = wave * 2 + (lane >> 5);
  const int sub = lane & 31, m = sub >> 2, j = sub & 3;
  const int qg = qBase + qloc;
  const int n = (qg >= LEN_IN) ? 1 : 0;
  const char* base = (const char*)value16 + (size_t)(n * 8 + m) * LEN_IN * 64 + j * 16;
  const int lb = qloc * 8 + m;

  float acc8[8] = {0.f, 0.f, 0.f, 0.f, 0.f, 0.f, 0.f, 0.f};

  // Named-register 2-deep pipeline over p = 0..15.
  hv8  va0, va1, va2, va3, vb0, vb1, vb2, vb3;
  float wa0, wa1, wa2, wa3, wb0, wb1, wb2, wb3;

  stage4(s_pair, lb, 0, base, va0, va1, va2, va3, wa0, wa1, wa2, wa3);

#pragma unroll
  for (int h = 0; h < 7; ++h) {
    stage4(s_pair, lb, 2 * h + 1, base, vb0, vb1, vb2, vb3, wb0, wb1, wb2, wb3);
    consume4(acc8, va0, va1, va2, va3, wa0, wa1, wa2, wa3);
    stage4(s_pair, lb, 2 * h + 2, base, va0, va1, va2, va3, wa0, wa1, wa2, wa3);
    consume4(acc8, vb0, vb1, vb2, vb3, wb0, wb1, wb2, wb3);
  }
  stage4(s_pair, lb, 15, base, vb0, vb1, vb2, vb3, wb0, wb1, wb2, wb3);
  consume4(acc8, va0, va1, va2, va3, wa0, wa1, wa2, wa3);
  consume4(acc8, vb0, vb1, vb2, vb3, wb0, wb1, wb2, wb3);

  hv8 o;
#pragma unroll
  for (int e = 0; e < 8; ++e) o[e] = (_Float16)acc8[e];
  *(hv8*)&outp16[(size_t)qg * 256 + m * 32 + j * 8] = o;
}

// ---------------------------------------------------------------------------
extern "C" void kernel_launch(void* const* d_in, const int* in_sizes, int n_in,
                              void* d_out, int out_size, void* d_ws, size_t ws_size,
                              hipStream_t stream) {
  const float* query   = (const float*)d_in[0];
  const float* refpts  = (const float*)d_in[1];
  const float* flatten = (const float*)d_in[2];
  const float* Wv   = (const float*)d_in[5];
  const float* bv   = (const float*)d_in[6];
  const float* Woff = (const float*)d_in[7];
  const float* boff = (const float*)d_in[8];
  const float* Wa   = (const float*)d_in[9];
  const float* ba   = (const float*)d_in[10];
  const float* Wo   = (const float*)d_in[11];
  const float* bo   = (const float*)d_in[12];
  float* out = (float*)d_out;

  // Workspace (~101 MB): value16 | coords | logits16 | outp16 | weights
  const size_t NE = (size_t)MROWS * 256;            // 11,141,120
  _Float16* value16  = (_Float16*)d_ws;             // NE halves (head planes)
  float*    coords   = (float*)(value16 + NE);      // NE floats
  _Float16* logits16 = (_Float16*)(coords + NE);    // NE/2 halves
  _Float16* outp16   = logits16 + NE / 2;           // NE halves
  _Float16* WvT      = outp16 + NE;                 // 256*256
  _Float16* WoffT2   = WvT + 256 * 256;             // 512*256 (hi|lo)
  _Float16* WaT      = WoffT2 + 512 * 256;          // 128*256 (contig after WoffT2!)
  _Float16* WoT      = WaT + 128 * 256;             // 256*256

  const dim3 blk(256);
  const int mtiles = MROWS / 64;   // 680

  cvt_weights<<<dim3(56), blk, 0, stream>>>(Wv, Woff, Wa, Wo, WvT, WoffT2, WaT, WoT);

  // value = f16(flatten @ Wv + bv) -> head planes
  gemm_pipe<256, 1, 2><<<dim3(mtiles, 2), blk, 0, stream>>>(flatten, WvT, bv, value16);
  // FUSED: coords = (query @ Woff + boff + ref) * W - 0.5  AND
  //        logits = f16(query @ Wa + ba)   -- one pass over query
  gemm_offs_logits<<<dim3(mtiles, 3), blk, 0, stream>>>(query, WoffT2, boff, ba, refpts,
                                                        coords, logits16);
  // sampling -> out_pre (f16)
  sample_kernel<<<dim3(MROWS / 8), blk, 0, stream>>>(value16, coords, logits16, outp16);
  // out = out_pre @ Wo + bo (fp32 to d_out)
  gemm_pipe<256, 0, 0><<<dim3(mtiles, 2), blk, 0, stream>>>(outp16, WoT, bo, out);
}

// Round 3
// 276.634 us; speedup vs baseline: 2.3789x; 2.3132x over previous
//
#include <hip/hip_runtime.h>
#include <cstdint>
#include <cstddef>

// Static problem geometry
#define LEN_IN  21760
#define BATCH   2
#define MROWS   (BATCH * LEN_IN)   // 43520 = 64 * 680
// Levels: (128,128),(64,64),(32,32),(16,16); starts 0,16384,20480,21504

typedef _Float16 hv8 __attribute__((ext_vector_type(8)));   // 8 f16
typedef float    fv4 __attribute__((ext_vector_type(4)));

#define WAIT_LGKM0() __builtin_amdgcn_s_waitcnt(0xC07F)   // lgkmcnt(0) only
#define RAW_BARRIER() __builtin_amdgcn_s_barrier()

// ---------------------------------------------------------------------------
// Weight prep: coalesced 64x64 LDS transpose. K-major [K][N] -> [N][K] f16.
// Woff -> f16-split: rows [0,256) = hi, [256,512) = lo residual.
// WaT lands contiguously after WoffT2 so the fused GEMM sees B rows 512..639.
// ---------------------------------------------------------------------------
__global__ __launch_bounds__(256) void cvt_weights(
    const float* __restrict__ Wv, const float* __restrict__ Woff,
    const float* __restrict__ Wa, const float* __restrict__ Wo,
    _Float16* __restrict__ WvT, _Float16* __restrict__ WoffT2,
    _Float16* __restrict__ WaT, _Float16* __restrict__ WoT)
{
  __shared__ float t[64][65];
  const int id = blockIdx.x, tid = threadIdx.x;
  const int c = tid & 63, r4 = tid >> 6;

  const float* src; _Float16* dst; int N; bool split = false; int nt, kt;
  if (id < 16)      { src = Wv;   dst = WvT;    N = 256; nt = id & 3;        kt = id >> 2; }
  else if (id < 32) { src = Woff; dst = WoffT2; N = 256; nt = (id - 16) & 3; kt = (id - 16) >> 2; split = true; }
  else if (id < 40) { src = Wa;   dst = WaT;    N = 128; nt = (id - 32) & 1; kt = (id - 32) >> 1; }
  else              { src = Wo;   dst = WoT;    N = 256; nt = (id - 40) & 3; kt = (id - 40) >> 2; }
  const int nb = nt * 64, kb = kt * 64;

#pragma unroll
  for (int rr = 0; rr < 16; ++rr) {
    const int r = rr * 4 + r4;
    t[r][c] = src[(size_t)(kb + r) * N + nb + c];
  }
  __syncthreads();
#pragma unroll
  for (int rr = 0; rr < 16; ++rr) {
    const int r = rr * 4 + r4;
    const float v = t[c][r];
    const _Float16 h = (_Float16)v;
    dst[(size_t)(nb + r) * 256 + kb + c] = h;
    if (split)
      dst[(size_t)(256 + nb + r) * 256 + kb + c] = (_Float16)(v - (float)h);
  }
}

// ---------------------------------------------------------------------------
// Pipelined f16 MFMA GEMM, 64 x 128 tile, 256 thr = 4 waves (cols 32 each).
// Register pipelines: A 3-deep (HBM, ~3-iter slack), B 2-deep (L2, ~2-iter).
// CRITICAL: loads issued in NEED ORDER (B(it+2) before A(it+3)) so in-order
// vmcnt retirement never drains young A loads.
// LDS double-buffered; ONE raw barrier per iter, lgkmcnt(0)-only wait.
// NTOT: full output width. AF32: A fp32 (cvt in regs) else f16.
// OUTMODE 0: fp32 row-major; 1: f16 row-major; 2: f16 head planes.
// ---------------------------------------------------------------------------
template<int NTOT, int AF32, int OUTMODE>
__global__ __launch_bounds__(256) void gemm_pipe(
    const void* __restrict__ Ap, const _Float16* __restrict__ Bt,
    const float* __restrict__ bias, void* __restrict__ Cout)
{
  __shared__ _Float16 As[2][64 * 40];
  __shared__ _Float16 Bs[2][128 * 40];

  const int tid = threadIdx.x, lane = tid & 63, wave = tid >> 6;
  const int l15 = lane & 15, quad = lane >> 4;
  const int wc = wave * 32;
  const int rowBase = blockIdx.x * 64;
  const int colBase = blockIdx.y * 128;
  const int rs = tid >> 2, ks = (tid & 3) * 8;

  const float*    A32 = (const float*)Ap;
  const _Float16* A16 = (const _Float16*)Ap;

  float4 pa[3][2]; hv8 pa16[3]; hv8 pb[2][2];

  auto issueA = [&](int it) {
    const int k0 = it * 32, s = it % 3;
    if constexpr (AF32) {
      pa[s][0] = *(const float4*)&A32[(size_t)(rowBase + rs) * 256 + k0 + ks];
      pa[s][1] = *(const float4*)&A32[(size_t)(rowBase + rs) * 256 + k0 + ks + 4];
    } else {
      pa16[s] = *(const hv8*)&A16[(size_t)(rowBase + rs) * 256 + k0 + ks];
    }
  };
  auto issueB = [&](int it) {
    const int k0 = it * 32, s = it & 1;
#pragma unroll
    for (int p = 0; p < 2; ++p)
      pb[s][p] = *(const hv8*)&Bt[(size_t)(colBase + p * 64 + rs) * 256 + k0 + ks];
  };

  // Preamble in need order
  issueA(0); issueB(0); issueA(1); issueB(1); issueA(2);

  fv4 acc[4][2] = {};

#pragma unroll
  for (int it = 0; it < 8; ++it) {
    const int sb = it & 1, sa = it % 3;
    if constexpr (AF32) {
      const float4 f0 = pa[sa][0], f1 = pa[sa][1];
      const float fa[8] = {f0.x, f0.y, f0.z, f0.w, f1.x, f1.y, f1.z, f1.w};
      hv8 h;
#pragma unroll
      for (int e = 0; e < 8; ++e) h[e] = (_Float16)fa[e];
      *(hv8*)&As[sb][rs * 40 + ks] = h;
    } else {
      *(hv8*)&As[sb][rs * 40 + ks] = pa16[sa];
    }
#pragma unroll
    for (int p = 0; p < 2; ++p)
      *(hv8*)&Bs[sb][(p * 64 + rs) * 40 + ks] = pb[sb][p];
    if (it + 2 < 8) issueB(it + 2);   // need order: B first,
    if (it + 3 < 8) issueA(it + 3);   // then A
    WAIT_LGKM0();
    RAW_BARRIER();

    hv8 af[4];
#pragma unroll
    for (int i = 0; i < 4; ++i)
      af[i] = *(const hv8*)&As[sb][(i * 16 + l15) * 40 + quad * 8];
#pragma unroll
    for (int j = 0; j < 2; ++j) {
      const hv8 bf = *(const hv8*)&Bs[sb][(wc + j * 16 + l15) * 40 + quad * 8];
#pragma unroll
      for (int i = 0; i < 4; ++i)
        acc[i][j] = __builtin_amdgcn_mfma_f32_16x16x32_f16(af[i], bf, acc[i][j], 0, 0, 0);
    }
    // Double buffer: reads of buf sb complete before next iter's lgkm wait,
    // so writes to buf sb at it+2 are safe with one barrier per iter.
  }

#pragma unroll
  for (int j = 0; j < 2; ++j) {
    const int col = colBase + wc + j * 16 + l15;
    const float bj = bias[col];
#pragma unroll
    for (int i = 0; i < 4; ++i)
#pragma unroll
      for (int rg = 0; rg < 4; ++rg) {
        const int row = rowBase + i * 16 + quad * 4 + rg;
        const float v = acc[i][j][rg] + bj;
        if constexpr (OUTMODE == 0) {
          ((float*)Cout)[(size_t)row * NTOT + col] = v;
        } else if constexpr (OUTMODE == 1) {
          ((_Float16*)Cout)[(size_t)row * NTOT + col] = (_Float16)v;
        } else {
          const int n = (row >= LEN_IN) ? 1 : 0;
          const int pix = row - n * LEN_IN;
          const int m = col >> 5, d = col & 31;
          ((_Float16*)Cout)[((size_t)(n * 8 + m) * LEN_IN + pix) * 32 + d] = (_Float16)v;
        }
      }
  }
}

// ---------------------------------------------------------------------------
// FUSED offsets + logits GEMM: one pass over query (A, fp32).
// Grid (680, 3): y=0,1 -> offset coord columns, f16-split A and B (3 MFMAs).
// y=2 -> logits columns, plain hi-only path (1 MFMA), f16 out.
// B2 = [640][256] f16: rows 0..255 Woff-hi, 256..511 Woff-lo, 512..639 Wa.
// Single-buffer LDS (30.7 KB), two raw barriers/iter, need-order pipeline.
// ---------------------------------------------------------------------------
__global__ __launch_bounds__(256) void gemm_offs_logits(
    const float* __restrict__ A, const _Float16* __restrict__ B2,
    const float* __restrict__ boff, const float* __restrict__ ba,
    const float* __restrict__ refpts,
    float* __restrict__ C, _Float16* __restrict__ logits16)
{
  __shared__ _Float16 Ash[64 * 40], Asl[64 * 40];
  __shared__ _Float16 Bs[256 * 40];   // offs: rows 0-127 hi, 128-255 lo. logits: rows 0-127.

  const bool offs = (blockIdx.y < 2);
  const int np = offs ? 4 : 2;        // B row-groups staged per iter
  const int tid = threadIdx.x, lane = tid & 63, wave = tid >> 6;
  const int l15 = lane & 15, quad = lane >> 4;
  const int wc = wave * 32;
  const int rowBase = blockIdx.x * 64;
  const int colBase = offs ? blockIdx.y * 128 : 0;
  const int rs = tid >> 2, ks = (tid & 3) * 8;

  float4 pa[3][2]; hv8 pb[2][4];

  auto issueA = [&](int it) {
    const int k0 = it * 32, s = it % 3;
    pa[s][0] = *(const float4*)&A[(size_t)(rowBase + rs) * 256 + k0 + ks];
    pa[s][1] = *(const float4*)&A[(size_t)(rowBase + rs) * 256 + k0 + ks + 4];
  };
  auto issueB = [&](int it) {
    const int k0 = it * 32, s = it & 1;
#pragma unroll
    for (int p = 0; p < 4; ++p) {
      if (p >= np) break;
      const int grow = offs
          ? ((p < 2) ? (colBase + p * 64 + rs) : (256 + colBase + (p - 2) * 64 + rs))
          : (512 + p * 64 + rs);
      pb[s][p] = *(const hv8*)&B2[(size_t)grow * 256 + k0 + ks];
    }
  };

  issueA(0); issueB(0); issueA(1); issueB(1); issueA(2);

  fv4 acc[4][2] = {};

#pragma unroll
  for (int it = 0; it < 8; ++it) {
    const int sa = it % 3, s2 = it & 1;
    {
      const float4 f0 = pa[sa][0], f1 = pa[sa][1];
      const float fa[8] = {f0.x, f0.y, f0.z, f0.w, f1.x, f1.y, f1.z, f1.w};
      hv8 hh, ll;
#pragma unroll
      for (int e = 0; e < 8; ++e) {
        hh[e] = (_Float16)fa[e];
        ll[e] = (_Float16)(fa[e] - (float)hh[e]);
      }
      *(hv8*)&Ash[rs * 40 + ks] = hh;
      if (offs) *(hv8*)&Asl[rs * 40 + ks] = ll;
    }
#pragma unroll
    for (int p = 0; p < 4; ++p) {
      if (p >= np) break;
      *(hv8*)&Bs[(p * 64 + rs) * 40 + ks] = pb[s2][p];
    }
    if (it + 2 < 8) issueB(it + 2);
    if (it + 3 < 8) issueA(it + 3);
    WAIT_LGKM0();
    RAW_BARRIER();

    hv8 ah[4];
#pragma unroll
    for (int i = 0; i < 4; ++i)
      ah[i] = *(const hv8*)&Ash[(i * 16 + l15) * 40 + quad * 8];

    if (offs) {
      hv8 al[4];
#pragma unroll
      for (int i = 0; i < 4; ++i)
        al[i] = *(const hv8*)&Asl[(i * 16 + l15) * 40 + quad * 8];
#pragma unroll
      for (int j = 0; j < 2; ++j) {
        const hv8 bh = *(const hv8*)&Bs[(wc + j * 16 + l15) * 40 + quad * 8];
        const hv8 bl = *(const hv8*)&Bs[(128 + wc + j * 16 + l15) * 40 + quad * 8];
#pragma unroll
        for (int i = 0; i < 4; ++i) {
          acc[i][j] = __builtin_amdgcn_mfma_f32_16x16x32_f16(ah[i], bh, acc[i][j], 0, 0, 0);
          acc[i][j] = __builtin_amdgcn_mfma_f32_16x16x32_f16(ah[i], bl, acc[i][j], 0, 0, 0);
          acc[i][j] = __builtin_amdgcn_mfma_f32_16x16x32_f16(al[i], bh, acc[i][j], 0, 0, 0);
        }
      }
    } else {
#pragma unroll
      for (int j = 0; j < 2; ++j) {
        const hv8 bh = *(const hv8*)&Bs[(wc + j * 16 + l15) * 40 + quad * 8];
#pragma unroll
        for (int i = 0; i < 4; ++i)
          acc[i][j] = __builtin_amdgcn_mfma_f32_16x16x32_f16(ah[i], bh, acc[i][j], 0, 0, 0);
      }
    }
    WAIT_LGKM0();   // frag reads done before next iter overwrites (single buf)
    RAW_BARRIER();
  }

  if (offs) {
    // col c = (((m*4+l)*4+p)*2+xy); write (acc + boff + ref) * W - 0.5
#pragma unroll
    for (int j = 0; j < 2; ++j) {
      const int c = colBase + wc + j * 16 + l15;
      const int xy = c & 1, l = (c >> 3) & 3;
      const float Wl = (float)(128 >> l);
      const float bj = boff[c];
#pragma unroll
      for (int i = 0; i < 4; ++i)
#pragma unroll
        for (int rg = 0; rg < 4; ++rg) {
          const int row = rowBase + i * 16 + quad * 4 + rg;
          const float ref = refpts[(size_t)row * 8 + l * 2 + xy];
          C[(size_t)row * 256 + c] = (acc[i][j][rg] + bj + ref) * Wl - 0.5f;
        }
    }
  } else {
#pragma unroll
    for (int j = 0; j < 2; ++j) {
      const int col = wc + j * 16 + l15;
      const float bj = ba[col];
#pragma unroll
      for (int i = 0; i < 4; ++i)
#pragma unroll
        for (int rg = 0; rg < 4; ++rg) {
          const int row = rowBase + i * 16 + quad * 4 + rg;
          logits16[(size_t)row * 128 + col] = (_Float16)(acc[i][j][rg] + bj);
        }
    }
  }
}

// ---------------------------------------------------------------------------
// Sampler (R0 baseline body: immediate-consume gathers — the compiler handles
// this well; both 2-deep register pipelines scratch-spilled ~1 GB. Only
// change vs R0: launch_bounds (256,6)->(256,8). LDS 20480 B = exactly
// 160KiB/8 and VGPR 24 << 64, so 8 blocks/CU fit.
// ---------------------------------------------------------------------------
__global__ __launch_bounds__(256, 8) void sample_kernel(
    const _Float16* __restrict__ value16,  // head planes
    const float* __restrict__ coords,      // (B, LQ, 256) pixel coords
    const _Float16* __restrict__ logits16, // (B, LQ, 128)
    _Float16* __restrict__ outp16)         // (B, LQ, 256)
{
  __shared__ unsigned s_pair[4096];
  __shared__ float    s_attn[1024];

  const int tid = threadIdx.x;
  const int qBase = blockIdx.x * 8;

  if (tid < 64) {   // softmax per (q,m) over 16
    const hv8* lp = (const hv8*)&logits16[(size_t)(qBase + (tid >> 3)) * 128 + (tid & 7) * 16];
    const hv8 w0 = lp[0], w1 = lp[1];
    float w[16];
#pragma unroll
    for (int e = 0; e < 8; ++e) { w[e] = (float)w0[e]; w[8 + e] = (float)w1[e]; }
    float mx = w[0];
#pragma unroll
    for (int i = 1; i < 16; ++i) mx = fmaxf(mx, w[i]);
    float sum = 0.f;
#pragma unroll
    for (int i = 0; i < 16; ++i) { w[i] = expf(w[i] - mx); sum += w[i]; }
    const float inv = 1.f / sum;
#pragma unroll
    for (int p = 0; p < 16; ++p) s_attn[p * 64 + tid] = w[p] * inv;
  }
  __syncthreads();

#pragma unroll
  for (int k = 0; k < 4; ++k) {
    const int i = tid + 256 * k;
    const int p = i >> 6, q = (i >> 3) & 7, m = i & 7;
    const int l = p >> 2, pp = p & 3;
    const int qg = qBase + q;
    const float2 of = *(const float2*)&coords[(size_t)qg * 256 + ((m * 4 + l) * 4 + pp) * 2];
    const float aw = s_attn[i];
    const int W = 128 >> l;
    const int st = (l == 0) ? 0 : (l == 1) ? 16384 : (l == 2) ? 20480 : 21504;
    const float xf = floorf(of.x), yf = floorf(of.y);
    const int x0 = (int)xf, y0 = (int)yf;
    const float wx = of.x - xf, wy = of.y - yf;
    uint4 rec;
    unsigned* rp = &rec.x;
#pragma unroll
    for (int c = 0; c < 4; ++c) {
      const int dx = c & 1, dy = c >> 1;
      const int xi = x0 + dx, yi = y0 + dy;
      const bool valid = (xi >= 0) & (xi < W) & (yi >= 0) & (yi < W);
      const float w = (dx ? wx : 1.f - wx) * (dy ? wy : 1.f - wy) * aw;
      union { _Float16 h; unsigned short s; } pk;
      pk.h = (_Float16)w;
      const unsigned idx = (unsigned)(st + yi * W + xi);
      rp[c] = valid ? (idx | ((unsigned)pk.s << 16)) : 0u;
    }
    *(uint4*)&s_pair[i * 4] = rec;
  }
  __syncthreads();

  const int wave = tid >> 6, lane = tid & 63;
  const int qloc = wave * 2 + (lane >> 5);
  const int sub = lane & 31, m = sub >> 2, j = sub & 3;
  const int qg = qBase + qloc;
  const int n = (qg >= LEN_IN) ? 1 : 0;
  const char* base = (const char*)value16 + (size_t)(n * 8 + m) * LEN_IN * 64 + j * 16;
  const int lb = qloc * 8 + m;

  float acc8[8] = {0.f, 0.f, 0.f, 0.f, 0.f, 0.f, 0.f, 0.f};
#pragma unroll 4
  for (int p = 0; p < 16; ++p) {
    const uint4 u4 = *(const uint4*)&s_pair[(p * 64 + lb) * 4];
    const unsigned uu[4] = {u4.x, u4.y, u4.z, u4.w};
#pragma unroll
    for (int c = 0; c < 4; ++c) {
      const unsigned u = uu[c];
      union { unsigned short s; _Float16 h; } pk;
      pk.s = (unsigned short)(u >> 16);
      const float w = (float)pk.h;
      const hv8 v = *(const hv8*)(base + (size_t)(u & 32767u) * 64);
#pragma unroll
      for (int e = 0; e < 8; ++e) acc8[e] = fmaf(w, (float)v[e], acc8[e]);
    }
  }

  hv8 o;
#pragma unroll
  for (int e = 0; e < 8; ++e) o[e] = (_Float16)acc8[e];
  *(hv8*)&outp16[(size_t)qg * 256 + m * 32 + j * 8] = o;
}

// ---------------------------------------------------------------------------
extern "C" void kernel_launch(void* const* d_in, const int* in_sizes, int n_in,
                              void* d_out, int out_size, void* d_ws, size_t ws_size,
                              hipStream_t stream) {
  const float* query   = (const float*)d_in[0];
  const float* refpts  = (const float*)d_in[1];
  const float* flatten = (const float*)d_in[2];
  const float* Wv   = (const float*)d_in[5];
  const float* bv   = (const float*)d_in[6];
  const float* Woff = (const float*)d_in[7];
  const float* boff = (const float*)d_in[8];
  const float* Wa   = (const float*)d_in[9];
  const float* ba   = (const float*)d_in[10];
  const float* Wo   = (const float*)d_in[11];
  const float* bo   = (const float*)d_in[12];
  float* out = (float*)d_out;

  // Workspace (~101 MB): value16 | coords | logits16 | outp16 | weights
  const size_t NE = (size_t)MROWS * 256;            // 11,141,120
  _Float16* value16  = (_Float16*)d_ws;             // NE halves (head planes)
  float*    coords   = (float*)(value16 + NE);      // NE floats
  _Float16* logits16 = (_Float16*)(coords + NE);    // NE/2 halves
  _Float16* outp16   = logits16 + NE / 2;           // NE halves
  _Float16* WvT      = outp16 + NE;                 // 256*256
  _Float16* WoffT2   = WvT + 256 * 256;             // 512*256 (hi|lo)
  _Float16* WaT      = WoffT2 + 512 * 256;          // 128*256 (contig after WoffT2!)
  _Float16* WoT      = WaT + 128 * 256;             // 256*256

  const dim3 blk(256);
  const int mtiles = MROWS / 64;   // 680

  cvt_weights<<<dim3(56), blk, 0, stream>>>(Wv, Woff, Wa, Wo, WvT, WoffT2, WaT, WoT);

  // value = f16(flatten @ Wv + bv) -> head planes
  gemm_pipe<256, 1, 2><<<dim3(mtiles, 2), blk, 0, stream>>>(flatten, WvT, bv, value16);
  // FUSED: coords = (query @ Woff + boff + ref) * W - 0.5  AND
  //        logits = f16(query @ Wa + ba)   -- one pass over query
  gemm_offs_logits<<<dim3(mtiles, 3), blk, 0, stream>>>(query, WoffT2, boff, ba, refpts,
                                                        coords, logits16);
  // sampling -> out_pre (f16)
  sample_kernel<<<dim3(MROWS / 8), blk, 0, stream>>>(value16, coords, logits16, outp16);
  // out = out_pre @ Wo + bo (fp32 to d_out)
  gemm_pipe<256, 0, 0><<<dim3(mtiles, 2), blk, 0, stream>>>(outp16, WoT, bo, out);
}